// Round 6
// baseline (1015.036 us; speedup 1.0000x reference)
//
#include <hip/hip_runtime.h>
#include <math.h>

// Problem dims
#define B_  2
#define S_  1024
#define H_  768
#define NH_ 12
#define DH_ 64
#define FF_ 3072
#define L_  4

typedef short v8s __attribute__((ext_vector_type(8)));
typedef float v4f __attribute__((ext_vector_type(4)));

static __device__ __forceinline__ unsigned short f2bf(float f) {
    unsigned int u = __float_as_uint(f);
    unsigned int r = (u + 0x7fffu + ((u >> 16) & 1u)) >> 16;
    return (unsigned short)r;
}
static __device__ __forceinline__ float bf2f(unsigned short u) {
    return __uint_as_float((unsigned int)u << 16);
}

#define GLOAD16(g, l) __builtin_amdgcn_global_load_lds( \
    (const __attribute__((address_space(1))) unsigned int*)(g), \
    (__attribute__((address_space(3))) unsigned int*)(l), 16, 0, 0)

// ---------------- fp32 -> bf16 convert ----------------
__global__ void conv_bf16_k(const float* __restrict__ in, unsigned short* __restrict__ out, int n) {
    int i = blockIdx.x * 256 + threadIdx.x;
    if (i < n) out[i] = f2bf(in[i]);
}

// ---------------- mask -> additive bf16 ----------------
__global__ void maskconv_k(const int* __restrict__ m, unsigned short* __restrict__ o, int n) {
    int i = blockIdx.x * 256 + threadIdx.x;
    if (i < n) o[i] = m[i] ? (unsigned short)0u : (unsigned short)0xC61Cu; // -9984 ~ -10000
}

// ---------------- fp32 [K,N] -> bf16 [N,K] transpose-convert ----------------
__global__ __launch_bounds__(256) void transpose_convert(
    const float* __restrict__ W, unsigned short* __restrict__ Wt,
    int K, int N, size_t in_lstride, size_t out_lstride)
{
    __shared__ float tile[32][33];
    const int l = blockIdx.z;
    const float* src = W + (size_t)l * in_lstride;
    unsigned short* dst = Wt + (size_t)l * out_lstride;
    const int k0 = blockIdx.x * 32;
    const int n0 = blockIdx.y * 32;
    const int t = threadIdx.x;
    const int tc = t & 31, tr = t >> 5;
#pragma unroll
    for (int i = 0; i < 4; ++i) {
        int r = tr + i * 8;
        tile[r][tc] = src[(size_t)(k0 + r) * N + n0 + tc];
    }
    __syncthreads();
#pragma unroll
    for (int i = 0; i < 4; ++i) {
        int r = tr + i * 8;
        dst[(size_t)(n0 + r) * K + k0 + tc] = f2bf(tile[tc][r]);
    }
}

// ---------------- bf16 MFMA GEMM, 128x128 tile, global_load_lds staging ----
// A: [M,K] bf16 row-major. Bt: [N,K] bf16 (W^T).
// SPLIT: blockIdx.z in {0,1} handles K-half [z*klen, z*klen+klen);
//        z==0 -> epilogue (bias/res/act) into out0; z==1 -> raw partial into out1.
template<int ACT, int OUT_BF, int NBIAS, int SPLIT>
__global__ __launch_bounds__(256) void gemm_k(
    const unsigned short* __restrict__ A,
    const unsigned short* __restrict__ Bt,
    const float* __restrict__ b0,
    const float* __restrict__ b1,
    const float* __restrict__ b2,
    const float* __restrict__ res,
    void* __restrict__ out0,
    float* __restrict__ out1,
    int M, int N, int K, int klen)
{
    __shared__ __align__(16) unsigned short As[128 * 32];
    __shared__ __align__(16) unsigned short Bs[128 * 32];
    const int t = threadIdx.x;
    const int m0 = blockIdx.x * 128;
    const int n0 = blockIdx.y * 128;
    const int kz = SPLIT ? blockIdx.z : 0;
    const int kstart = kz * klen;
    const int lane = t & 63;
    const int w = t >> 6;
    const int wm = w >> 1, wn = w & 1;
    const int l15 = lane & 15;
    const int kr8 = (lane >> 4) * 8;

    // ---- staging: per wave 2 row-groups of A and 2 of B (16 rows x 64B each).
    // LDS stays linear (global_load_lds lands at base + lane*16B); bank-conflict
    // swizzle is applied on the GLOBAL source chunk and undone on the ds_read:
    // chunk ^= (row>>1)&3 -> fragment reads become 2-way (free) instead of 8-way.
    const int rg = lane >> 2;       // row within 16-row group
    const int cg = lane & 3;        // 16B chunk within 64B row slice
    const int rA0 = (w * 2 + 0) * 16 + rg;
    const int rA1 = (w * 2 + 1) * 16 + rg;
    const int cs0 = (cg ^ ((rA0 >> 1) & 3)) * 8;
    const int cs1 = (cg ^ ((rA1 >> 1) & 3)) * 8;
    const unsigned short* gA0 = A  + (size_t)(m0 + rA0) * K + kstart + cs0;
    const unsigned short* gA1 = A  + (size_t)(m0 + rA1) * K + kstart + cs1;
    const unsigned short* gB0 = Bt + (size_t)(n0 + rA0) * K + kstart + cs0;
    const unsigned short* gB1 = Bt + (size_t)(n0 + rA1) * K + kstart + cs1;
    unsigned short* lA0 = &As[(w * 2 + 0) * 16 * 32];
    unsigned short* lA1 = &As[(w * 2 + 1) * 16 * 32];
    unsigned short* lB0 = &Bs[(w * 2 + 0) * 16 * 32];
    unsigned short* lB1 = &Bs[(w * 2 + 1) * 16 * 32];

    const int abase = l15 * 32 + (kr8 ^ (((l15 >> 1) & 3) << 3));

    v4f acc[4][4] = {};

    for (int k0 = 0; k0 < klen; k0 += 32) {
        __syncthreads();
        GLOAD16(gA0 + k0, lA0);
        GLOAD16(gA1 + k0, lA1);
        GLOAD16(gB0 + k0, lB0);
        GLOAD16(gB1 + k0, lB1);
        __syncthreads();
        v8s a[4], b[4];
#pragma unroll
        for (int i = 0; i < 4; ++i) a[i] = *(const v8s*)&As[(wm * 64 + i * 16) * 32 + abase];
#pragma unroll
        for (int i = 0; i < 4; ++i) b[i] = *(const v8s*)&Bs[(wn * 64 + i * 16) * 32 + abase];
#pragma unroll
        for (int fm = 0; fm < 4; ++fm)
#pragma unroll
            for (int fn = 0; fn < 4; ++fn)
                acc[fm][fn] = __builtin_amdgcn_mfma_f32_16x16x32_bf16(a[fm], b[fn], acc[fm][fn], 0, 0, 0);
    }

    const int rb = (lane >> 4) * 4;
#pragma unroll
    for (int fm = 0; fm < 4; ++fm)
#pragma unroll
        for (int fn = 0; fn < 4; ++fn)
#pragma unroll
            for (int i = 0; i < 4; ++i) {
                const int row = m0 + wm * 64 + fm * 16 + rb + i;
                const int col = n0 + wn * 64 + fn * 16 + l15;
                float v = acc[fm][fn][i];
                const size_t oi = (size_t)row * N + col;
                if (!SPLIT || kz == 0) {
                    float bb;
                    if (NBIAS == 3) {
                        int which = (col >= 1536) ? 2 : (col >= 768 ? 1 : 0);
                        const float* bp = (which == 0) ? b0 : ((which == 1) ? b1 : b2);
                        bb = bp[col - which * 768];
                    } else {
                        bb = b0[col];
                    }
                    v += bb;
                    if (res) v += res[oi];
                    if (ACT == 1) v = 0.5f * v * (1.0f + erff(v * 0.70710678118654752f));
                    if (OUT_BF) ((unsigned short*)out0)[oi] = f2bf(v);
                    else        ((float*)out0)[oi] = v;
                } else {
                    out1[oi] = v;
                }
            }
}

// ---------------- LayerNorm (row = 768), x = ina + inb, writes fp32 + bf16 ----
__global__ __launch_bounds__(256) void ln_k(
    const float* __restrict__ ina, const float* __restrict__ inb,
    const float* __restrict__ g, const float* __restrict__ be,
    float* __restrict__ outf, unsigned short* __restrict__ outb)
{
    const int row = blockIdx.x;
    const float* xa = ina + (size_t)row * H_;
    const float* xb = inb + (size_t)row * H_;
    const int t = threadIdx.x;
    const int wave = t >> 6, lane = t & 63;
    float v0 = xa[t] + xb[t];
    float v1 = xa[t + 256] + xb[t + 256];
    float v2 = xa[t + 512] + xb[t + 512];
    float s = v0 + v1 + v2;
    float s2 = v0 * v0 + v1 * v1 + v2 * v2;
#pragma unroll
    for (int o = 32; o; o >>= 1) { s += __shfl_xor(s, o); s2 += __shfl_xor(s2, o); }
    __shared__ float rs[4], rq[4];
    if (lane == 0) { rs[wave] = s; rq[wave] = s2; }
    __syncthreads();
    s  = rs[0] + rs[1] + rs[2] + rs[3];
    s2 = rq[0] + rq[1] + rq[2] + rq[3];
    const float mean = s * (1.0f / 768.0f);
    float var = s2 * (1.0f / 768.0f) - mean * mean;
    var = fmaxf(var, 0.0f);
    const float inv = rsqrtf(var + 1e-12f);
#pragma unroll
    for (int i = 0; i < 3; ++i) {
        int c = t + i * 256;
        float vv = (i == 0) ? v0 : ((i == 1) ? v1 : v2);
        float y = (vv - mean) * inv * g[c] + be[c];
        outf[(size_t)row * H_ + c] = y;
        outb[(size_t)row * H_ + c] = f2bf(y);
    }
}

// ---------------- Flash attention, bf16 MFMA, KV-split x2 ----------------
// Grid: (S/64, NH, B), 512 threads = 8 waves. Waves 0-3 (half 0) process keys
// [0,512), waves 4-7 keys [512,1024) on private LDS halves; states merged at end.
// Each wave owns 16 q-rows. Reg-prefetch (T14): next tile's K/V global loads
// issue before compute so HBM latency hides under QK/softmax/PV.
__global__ __launch_bounds__(512) void fattn_k(
    const unsigned short* __restrict__ qkv,
    const unsigned short* __restrict__ madd,
    unsigned short* __restrict__ ctx)
{
    const int qt = blockIdx.x, h = blockIdx.y, b = blockIdx.z;
    const int q0 = qt * 64;
    const int t = threadIdx.x;
    const int w = t >> 6, lane = t & 63;
    const int half = w >> 2, w4 = w & 3;
    const int l15 = lane & 15;
    const int kr8 = (lane >> 4) * 8;
    const int rb  = (lane >> 4) * 4;
    const int wq0 = w4 * 16;

    // LDS carve: Ks[2][64][72] | VtL[2][4096] | Ps[2][64][72]
    __shared__ __align__(16) unsigned char smem[53248];
    unsigned short* KsH = (unsigned short*)(smem)         + (size_t)half * (64 * 72);
    unsigned short* VtH = (unsigned short*)(smem + 18432) + (size_t)half * 4096;
    unsigned short* PsH = (unsigned short*)(smem + 34816) + (size_t)half * (64 * 72);

    const size_t rstr = 2304;
    const unsigned short* base = qkv + (size_t)b * S_ * rstr + h * 64;

    // Q fragments (wave's 16 rows)
    v8s qf0, qf1;
    {
        const unsigned short* qp = base + (size_t)(q0 + wq0 + l15) * rstr + kr8;
        qf0 = *(const v8s*)qp;
        qf1 = *(const v8s*)(qp + 32);
    }

    // staging assignment (per half: 256 threads)
    const int tl  = t & 255;
    const int skp = tl >> 3;        // 0..31
    const int sd0 = (tl & 7) * 8;   // 0..56
    const unsigned short* kbase = base + 768  + (size_t)(half * 512 + skp) * rstr + sd0;
    const unsigned short* vbase = base + 1536 + (size_t)(half * 512 + 2 * skp) * rstr + sd0;
    const size_t kstep = (size_t)64 * rstr;

    float m_[4], l_[4];
    v4f accO[4];
#pragma unroll
    for (int i = 0; i < 4; ++i) { m_[i] = -3.0e38f; l_[i] = 0.f; }
#pragma unroll
    for (int f = 0; f < 4; ++f) accO[f] = (v4f){0.f, 0.f, 0.f, 0.f};

    const unsigned short* mrow[4];
#pragma unroll
    for (int i = 0; i < 4; ++i)
        mrow[i] = madd + ((size_t)(b * S_) + q0 + wq0 + rb + i) * S_ + half * 512;

    v8s kA0, kA1, vA0, vA1, kB0, kB1, vB0, vB1;
    // prefetch tile 0 -> set A
    kA0 = *(const v8s*)(kbase);
    kA1 = *(const v8s*)(kbase + 32 * rstr);
    vA0 = *(const v8s*)(vbase);
    vA1 = *(const v8s*)(vbase + rstr);

    for (int kt = 0; kt < 8; ++kt) {
        const int k0 = kt * 64;
        __syncthreads();
        // ---- write current regs -> LDS; issue next tile's loads ----
        if ((kt & 1) == 0) {
            *(v8s*)&KsH[skp * 72 + sd0] = kA0;
            *(v8s*)&KsH[(skp + 32) * 72 + sd0] = kA1;
#pragma unroll
            for (int j = 0; j < 8; ++j) {
                const int d = sd0 + j;
                const int sw = ((d & 7) ^ (d >> 3)) << 3;
                unsigned int pk = ((unsigned int)(unsigned short)vA1[j] << 16) | (unsigned short)vA0[j];
                *(unsigned int*)&VtH[(size_t)d * 64 + ((2 * skp) ^ sw)] = pk;
            }
            if (kt < 7) {
                const unsigned short* kp = kbase + (size_t)(kt + 1) * kstep;
                const unsigned short* vp = vbase + (size_t)(kt + 1) * kstep;
                kB0 = *(const v8s*)kp;
                kB1 = *(const v8s*)(kp + 32 * rstr);
                vB0 = *(const v8s*)vp;
                vB1 = *(const v8s*)(vp + rstr);
            }
        } else {
            *(v8s*)&KsH[skp * 72 + sd0] = kB0;
            *(v8s*)&KsH[(skp + 32) * 72 + sd0] = kB1;
#pragma unroll
            for (int j = 0; j < 8; ++j) {
                const int d = sd0 + j;
                const int sw = ((d & 7) ^ (d >> 3)) << 3;
                unsigned int pk = ((unsigned int)(unsigned short)vB1[j] << 16) | (unsigned short)vB0[j];
                *(unsigned int*)&VtH[(size_t)d * 64 + ((2 * skp) ^ sw)] = pk;
            }
            if (kt < 7) {
                const unsigned short* kp = kbase + (size_t)(kt + 1) * kstep;
                const unsigned short* vp = vbase + (size_t)(kt + 1) * kstep;
                kA0 = *(const v8s*)kp;
                kA1 = *(const v8s*)(kp + 32 * rstr);
                vA0 = *(const v8s*)vp;
                vA1 = *(const v8s*)(vp + rstr);
            }
        }
        __syncthreads();

        // ---- QK^T ----
        v4f s4[4];
#pragma unroll
        for (int f = 0; f < 4; ++f) s4[f] = (v4f){0.f, 0.f, 0.f, 0.f};
#pragma unroll
        for (int ks = 0; ks < 2; ++ks) {
            v8s qv = ks ? qf1 : qf0;
#pragma unroll
            for (int f = 0; f < 4; ++f) {
                v8s kf = *(const v8s*)&KsH[(f * 16 + l15) * 72 + ks * 32 + kr8];
                s4[f] = __builtin_amdgcn_mfma_f32_16x16x32_bf16(qv, kf, s4[f], 0, 0, 0);
            }
        }

        // ---- mask + scale + online softmax ----
        float p[4][4];
        float mx[4];
#pragma unroll
        for (int i = 0; i < 4; ++i) mx[i] = -3.0e38f;
#pragma unroll
        for (int f = 0; f < 4; ++f)
#pragma unroll
            for (int i = 0; i < 4; ++i) {
                float v = s4[f][i] * 0.125f + bf2f(mrow[i][k0 + f * 16 + l15]);
                p[f][i] = v;
                mx[i] = fmaxf(mx[i], v);
            }
#pragma unroll
        for (int o = 8; o; o >>= 1)
#pragma unroll
            for (int i = 0; i < 4; ++i) mx[i] = fmaxf(mx[i], __shfl_xor(mx[i], o));
        float corr[4], rsum[4];
#pragma unroll
        for (int i = 0; i < 4; ++i) {
            float mn = fmaxf(m_[i], mx[i]);
            corr[i] = __expf(m_[i] - mn);
            m_[i] = mn;
            rsum[i] = 0.f;
        }
#pragma unroll
        for (int f = 0; f < 4; ++f)
#pragma unroll
            for (int i = 0; i < 4; ++i) {
                float e = __expf(p[f][i] - m_[i]);
                p[f][i] = e;
                rsum[i] += e;
            }
#pragma unroll
        for (int o = 8; o; o >>= 1)
#pragma unroll
            for (int i = 0; i < 4; ++i) rsum[i] += __shfl_xor(rsum[i], o);
#pragma unroll
        for (int i = 0; i < 4; ++i) l_[i] = l_[i] * corr[i] + rsum[i];
#pragma unroll
        for (int f = 0; f < 4; ++f)
#pragma unroll
            for (int i = 0; i < 4; ++i) accO[f][i] *= corr[i];

        // ---- P -> LDS (wave-private rows) ----
#pragma unroll
        for (int f = 0; f < 4; ++f)
#pragma unroll
            for (int i = 0; i < 4; ++i)
                PsH[(wq0 + rb + i) * 72 + f * 16 + l15] = f2bf(p[f][i]);

        // ---- PV ----
#pragma unroll
        for (int ks = 0; ks < 2; ++ks) {
            v8s pf = *(const v8s*)&PsH[(wq0 + l15) * 72 + ks * 32 + kr8];
#pragma unroll
            for (int f = 0; f < 4; ++f) {
                const int d = f * 16 + l15;
                const int sw = ((d & 7) ^ (d >> 3)) << 3;
                v8s vf = *(const v8s*)&VtH[(size_t)d * 64 + ((ks * 32 + kr8) ^ sw)];
                accO[f] = __builtin_amdgcn_mfma_f32_16x16x32_bf16(pf, vf, accO[f], 0, 0, 0);
            }
        }
    }

    // ---- merge the two KV-halves (online-softmax state merge) ----
    __syncthreads();
    float* Mb = (float*)smem;   // [4][64][26] floats, overlays Ks/Vt (dead now)
    const int mstr = 26;
    if (half == 1) {
        float* p = Mb + ((size_t)(w4 * 64 + lane)) * mstr;
#pragma unroll
        for (int i = 0; i < 4; ++i) { p[i] = m_[i]; p[4 + i] = l_[i]; }
#pragma unroll
        for (int f = 0; f < 4; ++f)
#pragma unroll
            for (int i = 0; i < 4; ++i) p[8 + f * 4 + i] = accO[f][i];
    }
    __syncthreads();
    if (half == 0) {
        const float* p = Mb + ((size_t)(w4 * 64 + lane)) * mstr;
        float c0[4], c1[4];
#pragma unroll
        for (int i = 0; i < 4; ++i) {
            float m1 = p[i], l1 = p[4 + i];
            float mm = fmaxf(m_[i], m1);
            c0[i] = __expf(m_[i] - mm);
            c1[i] = __expf(m1 - mm);
            l_[i] = l_[i] * c0[i] + l1 * c1[i];
            m_[i] = mm;
        }
#pragma unroll
        for (int f = 0; f < 4; ++f)
#pragma unroll
            for (int i = 0; i < 4; ++i) {
                float o = (accO[f][i] * c0[i] + p[8 + f * 4 + i] * c1[i]) / l_[i];
                size_t row = (size_t)(b * S_) + q0 + wq0 + rb + i;
                ctx[row * 768 + h * 64 + f * 16 + l15] = f2bf(o);
            }
    }
}

extern "C" void kernel_launch(void* const* d_in, const int* in_sizes, int n_in,
                              void* d_out, int out_size, void* d_ws, size_t ws_size,
                              hipStream_t stream)
{
    const float* x   = (const float*)d_in[0];
    const int*   mask= (const int*)  d_in[1];
    const float* Wq  = (const float*)d_in[2];
    const float* bq  = (const float*)d_in[3];
    const float* Wk  = (const float*)d_in[4];
    const float* bk  = (const float*)d_in[5];
    const float* Wv  = (const float*)d_in[6];
    const float* bv  = (const float*)d_in[7];
    const float* Wao = (const float*)d_in[8];
    const float* bao = (const float*)d_in[9];
    const float* g1  = (const float*)d_in[10];
    const float* b1  = (const float*)d_in[11];
    const float* Wi  = (const float*)d_in[12];
    const float* bi  = (const float*)d_in[13];
    const float* Wfo = (const float*)d_in[14];
    const float* bfo = (const float*)d_in[15];
    const float* g2  = (const float*)d_in[16];
    const float* b2  = (const float*)d_in[17];
    float* out = (float*)d_out;

    const int M = B_ * S_; // 2048
    char* basep = (char*)d_ws;
    size_t off = 0;
    auto alloc = [&](size_t bytes) -> char* {
        char* p = basep + off;
        off = (off + bytes + 255) & ~(size_t)255;
        return p;
    };

    unsigned short* WqkvT = (unsigned short*)alloc((size_t)L_ * 2304 * 768 * 2);
    unsigned short* WaoT  = (unsigned short*)alloc((size_t)L_ * 768 * 768 * 2);
    unsigned short* WiT   = (unsigned short*)alloc((size_t)L_ * 3072 * 768 * 2);
    unsigned short* WfoT  = (unsigned short*)alloc((size_t)L_ * 768 * 3072 * 2);
    unsigned short* h_bf  = (unsigned short*)alloc((size_t)M * 768 * 2);
    unsigned short* qkvbf = (unsigned short*)alloc((size_t)M * 2304 * 2);  // t1b aliases this (dead when used)
    unsigned short* ctxbf = (unsigned short*)alloc((size_t)M * 768 * 2);
    float* t1a            = (float*)alloc((size_t)M * 768 * 4);
    float* attnf          = (float*)alloc((size_t)M * 768 * 4);
    unsigned short* attnbf= (unsigned short*)alloc((size_t)M * 768 * 2);
    unsigned short* interbf = (unsigned short*)alloc((size_t)M * FF_ * 2);
    unsigned short* madd  = (unsigned short*)alloc((size_t)B_ * S_ * S_ * 2);
    float* t1b = (float*)(void*)qkvbf;   // alias: qkvbf dead during AO/FFN2/LN
    // rolling hidden state (fp32) lives in d_out; final layer's LN2 writes the answer

    dim3 tb(256);
    transpose_convert<<<dim3(24, 24, L_), tb, 0, stream>>>(Wq,  WqkvT + 0,          768,  768, (size_t)768 * 768,  (size_t)2304 * 768);
    transpose_convert<<<dim3(24, 24, L_), tb, 0, stream>>>(Wk,  WqkvT + 768 * 768,  768,  768, (size_t)768 * 768,  (size_t)2304 * 768);
    transpose_convert<<<dim3(24, 24, L_), tb, 0, stream>>>(Wv,  WqkvT + 1536 * 768, 768,  768, (size_t)768 * 768,  (size_t)2304 * 768);
    transpose_convert<<<dim3(24, 24, L_), tb, 0, stream>>>(Wao, WaoT,               768,  768, (size_t)768 * 768,  (size_t)768 * 768);
    transpose_convert<<<dim3(24, 96, L_), tb, 0, stream>>>(Wi,  WiT,                768, 3072, (size_t)768 * 3072, (size_t)3072 * 768);
    transpose_convert<<<dim3(96, 24, L_), tb, 0, stream>>>(Wfo, WfoT,              3072,  768, (size_t)3072 * 768, (size_t)768 * 3072);

    conv_bf16_k<<<(M * 768 + 255) / 256, 256, 0, stream>>>(x, h_bf, M * 768);
    maskconv_k<<<(B_ * S_ * S_ + 255) / 256, 256, 0, stream>>>(mask, madd, B_ * S_ * S_);

    const float* hres = x;
    for (int l = 0; l < L_; ++l) {
        // QKV projection (fused, N=2304, bf16 out)
        gemm_k<0, 1, 3, 0><<<dim3(16, 18), tb, 0, stream>>>(
            h_bf, WqkvT + (size_t)l * 2304 * 768,
            bq + l * 768, bk + l * 768, bv + l * 768, nullptr, qkvbf, nullptr, M, 2304, 768, 768);
        // Flash attention (bf16 MFMA, KV-split x2)
        fattn_k<<<dim3(S_ / 64, NH_, B_), dim3(512), 0, stream>>>(qkvbf, madd, ctxbf);
        // Attention output projection + residual, split-K x2
        gemm_k<0, 0, 1, 1><<<dim3(16, 6, 2), tb, 0, stream>>>(
            ctxbf, WaoT + (size_t)l * 768 * 768,
            bao + l * 768, nullptr, nullptr, hres, t1a, t1b, M, 768, 768, 384);
        ln_k<<<M, tb, 0, stream>>>(t1a, t1b, g1 + l * 768, b1 + l * 768, attnf, attnbf);
        // FFN1 + GELU (bf16 out)
        gemm_k<1, 1, 1, 0><<<dim3(16, 24), tb, 0, stream>>>(
            attnbf, WiT + (size_t)l * 3072 * 768,
            bi + l * 3072, nullptr, nullptr, nullptr, interbf, nullptr, M, 3072, 768, 768);
        // FFN2 + residual, split-K x2
        gemm_k<0, 0, 1, 1><<<dim3(16, 6, 2), tb, 0, stream>>>(
            interbf, WfoT + (size_t)l * 3072 * 768,
            bfo + l * 768, nullptr, nullptr, attnf, t1a, t1b, M, 768, 3072, 1536);
        ln_k<<<M, tb, 0, stream>>>(t1a, t1b, g2 + l * 768, b2 + l * 768, out, h_bf);
        hres = out;
    }
}

// Round 7
// 768.817 us; speedup vs baseline: 1.3203x; 1.3203x over previous
//
#include <hip/hip_runtime.h>
#include <math.h>

// Problem dims
#define B_  2
#define S_  1024
#define H_  768
#define NH_ 12
#define DH_ 64
#define FF_ 3072
#define L_  4

typedef short v8s __attribute__((ext_vector_type(8)));
typedef float v4f __attribute__((ext_vector_type(4)));

static __device__ __forceinline__ unsigned short f2bf(float f) {
    unsigned int u = __float_as_uint(f);
    unsigned int r = (u + 0x7fffu + ((u >> 16) & 1u)) >> 16;
    return (unsigned short)r;
}
static __device__ __forceinline__ float bf2f(unsigned short u) {
    return __uint_as_float((unsigned int)u << 16);
}

#define GLOAD16(g, l) __builtin_amdgcn_global_load_lds( \
    (const __attribute__((address_space(1))) unsigned int*)(g), \
    (__attribute__((address_space(3))) unsigned int*)(l), 16, 0, 0)

// ---------------- fp32 -> bf16 convert ----------------
__global__ void conv_bf16_k(const float* __restrict__ in, unsigned short* __restrict__ out, int n) {
    int i = blockIdx.x * 256 + threadIdx.x;
    if (i < n) out[i] = f2bf(in[i]);
}

// ---------------- mask -> additive bf16 ----------------
__global__ void maskconv_k(const int* __restrict__ m, unsigned short* __restrict__ o, int n) {
    int i = blockIdx.x * 256 + threadIdx.x;
    if (i < n) o[i] = m[i] ? (unsigned short)0u : (unsigned short)0xC61Cu; // -9984 ~ -10000
}

// ---------------- fp32 [K,N] -> bf16 [N,K] transpose-convert ----------------
__global__ __launch_bounds__(256) void transpose_convert(
    const float* __restrict__ W, unsigned short* __restrict__ Wt,
    int K, int N, size_t in_lstride, size_t out_lstride)
{
    __shared__ float tile[32][33];
    const int l = blockIdx.z;
    const float* src = W + (size_t)l * in_lstride;
    unsigned short* dst = Wt + (size_t)l * out_lstride;
    const int k0 = blockIdx.x * 32;
    const int n0 = blockIdx.y * 32;
    const int t = threadIdx.x;
    const int tc = t & 31, tr = t >> 5;
#pragma unroll
    for (int i = 0; i < 4; ++i) {
        int r = tr + i * 8;
        tile[r][tc] = src[(size_t)(k0 + r) * N + n0 + tc];
    }
    __syncthreads();
#pragma unroll
    for (int i = 0; i < 4; ++i) {
        int r = tr + i * 8;
        dst[(size_t)(n0 + r) * K + k0 + tc] = f2bf(tile[tc][r]);
    }
}

// ---------------- bf16 MFMA GEMM, 128x64 tile, BK=64, 2-phase dbuf ----------
// A: [M,K] bf16 row-major. Bt: [N,K] bf16 (W^T).
// Schedule per K-step: barrier (vmcnt0 -> buf[cur] ready) ; issue next tile's
// global_load_lds into buf[cur^1] ; ds_read+MFMA from buf[cur] ; flip.
// Next-tile HBM latency hides under the compute phase (T3-lite 2-phase).
// LDS stays linear for the DMA; bank swizzle applied on the GLOBAL source
// chunk (chunk ^= row&7) and undone on the ds_read -> 2-way (free) reads.
// SPLIT: blockIdx.z in {0,1} handles K-half [z*klen, z*klen+klen);
//        z==0 -> epilogue (bias/res/act) into out0; z==1 -> raw partial into out1.
template<int ACT, int OUT_BF, int NBIAS, int SPLIT>
__global__ __launch_bounds__(256) void gemm_k(
    const unsigned short* __restrict__ A,
    const unsigned short* __restrict__ Bt,
    const float* __restrict__ b0,
    const float* __restrict__ b1,
    const float* __restrict__ b2,
    const float* __restrict__ res,
    void* __restrict__ out0,
    float* __restrict__ out1,
    int M, int N, int K, int klen)
{
    __shared__ __align__(16) unsigned short As[2][128 * 64];
    __shared__ __align__(16) unsigned short Bs[2][64 * 64];
    const int t = threadIdx.x;
    const int m0 = blockIdx.x * 128;
    const int n0 = blockIdx.y * 64;
    const int kz = SPLIT ? blockIdx.z : 0;
    const int kstart = kz * klen;
    const int lane = t & 63;
    const int w = t >> 6;
    const int wm = w >> 1, wn = w & 1;
    const int l15 = lane & 15;
    const int q4  = lane >> 4;      // 0..3

    // staging: 1536 16B-chunks per tile (A 1024 + B 512) = 6 per thread.
    // chunk c: row = c>>3, cc = c&7; global col-chunk = cc ^ (row&7).
    const unsigned short* gA[4];
    const unsigned short* gB[2];
#pragma unroll
    for (int i = 0; i < 4; ++i) {
        int c = t + i * 256;
        int r = c >> 3, cc = c & 7;
        gA[i] = A + (size_t)(m0 + r) * K + kstart + ((cc ^ (r & 7)) << 3);
    }
#pragma unroll
    for (int i = 0; i < 2; ++i) {
        int c = t + i * 256;
        int r = c >> 3, cc = c & 7;
        gB[i] = Bt + (size_t)(n0 + r) * K + kstart + ((cc ^ (r & 7)) << 3);
    }
    const int ldsW = w * 512;       // this wave's 64-chunk slot (elements)

    v4f acc[4][2] = {};
    const int nt = klen >> 6;

    // prologue: stage tile 0 -> buf 0
#pragma unroll
    for (int i = 0; i < 4; ++i) GLOAD16(gA[i], &As[0][i * 2048 + ldsW]);
#pragma unroll
    for (int i = 0; i < 2; ++i) GLOAD16(gB[i], &Bs[0][i * 2048 + ldsW]);

    int cur = 0;
    for (int kt = 0; kt < nt; ++kt) {
        __syncthreads();            // drains vmcnt(0): buf[cur] ready; prior reads done
        if (kt + 1 < nt) {
            const size_t go = (size_t)(kt + 1) << 6;
#pragma unroll
            for (int i = 0; i < 4; ++i) GLOAD16(gA[i] + go, &As[cur ^ 1][i * 2048 + ldsW]);
#pragma unroll
            for (int i = 0; i < 2; ++i) GLOAD16(gB[i] + go, &Bs[cur ^ 1][i * 2048 + ldsW]);
        }
        const unsigned short* as = As[cur];
        const unsigned short* bs = Bs[cur];
#pragma unroll
        for (int ks = 0; ks < 2; ++ks) {
            v8s af[4], bf[2];
#pragma unroll
            for (int i = 0; i < 4; ++i) {
                int r = wm * 64 + i * 16 + l15;
                af[i] = *(const v8s*)&as[r * 64 + ((((ks << 2) + q4) ^ (r & 7)) << 3)];
            }
#pragma unroll
            for (int i = 0; i < 2; ++i) {
                int r = wn * 32 + i * 16 + l15;
                bf[i] = *(const v8s*)&bs[r * 64 + ((((ks << 2) + q4) ^ (r & 7)) << 3)];
            }
#pragma unroll
            for (int fm = 0; fm < 4; ++fm)
#pragma unroll
                for (int fn = 0; fn < 2; ++fn)
                    acc[fm][fn] = __builtin_amdgcn_mfma_f32_16x16x32_bf16(af[fm], bf[fn], acc[fm][fn], 0, 0, 0);
        }
        cur ^= 1;
    }

    const int rb = q4 * 4;
#pragma unroll
    for (int fm = 0; fm < 4; ++fm)
#pragma unroll
        for (int fn = 0; fn < 2; ++fn)
#pragma unroll
            for (int i = 0; i < 4; ++i) {
                const int row = m0 + wm * 64 + fm * 16 + rb + i;
                const int col = n0 + wn * 32 + fn * 16 + l15;
                float v = acc[fm][fn][i];
                const size_t oi = (size_t)row * N + col;
                if (!SPLIT || kz == 0) {
                    float bb;
                    if (NBIAS == 3) {
                        int which = (col >= 1536) ? 2 : (col >= 768 ? 1 : 0);
                        const float* bp = (which == 0) ? b0 : ((which == 1) ? b1 : b2);
                        bb = bp[col - which * 768];
                    } else {
                        bb = b0[col];
                    }
                    v += bb;
                    if (res) v += res[oi];
                    if (ACT == 1) v = 0.5f * v * (1.0f + erff(v * 0.70710678118654752f));
                    if (OUT_BF) ((unsigned short*)out0)[oi] = f2bf(v);
                    else        ((float*)out0)[oi] = v;
                } else {
                    out1[oi] = v;
                }
            }
}

// ---------------- LayerNorm (row = 768), x = ina + inb, writes fp32 + bf16 ----
__global__ __launch_bounds__(256) void ln_k(
    const float* __restrict__ ina, const float* __restrict__ inb,
    const float* __restrict__ g, const float* __restrict__ be,
    float* __restrict__ outf, unsigned short* __restrict__ outb)
{
    const int row = blockIdx.x;
    const float* xa = ina + (size_t)row * H_;
    const float* xb = inb + (size_t)row * H_;
    const int t = threadIdx.x;
    const int wave = t >> 6, lane = t & 63;
    float v0 = xa[t] + xb[t];
    float v1 = xa[t + 256] + xb[t + 256];
    float v2 = xa[t + 512] + xb[t + 512];
    float s = v0 + v1 + v2;
    float s2 = v0 * v0 + v1 * v1 + v2 * v2;
#pragma unroll
    for (int o = 32; o; o >>= 1) { s += __shfl_xor(s, o); s2 += __shfl_xor(s2, o); }
    __shared__ float rs[4], rq[4];
    if (lane == 0) { rs[wave] = s; rq[wave] = s2; }
    __syncthreads();
    s  = rs[0] + rs[1] + rs[2] + rs[3];
    s2 = rq[0] + rq[1] + rq[2] + rq[3];
    const float mean = s * (1.0f / 768.0f);
    float var = s2 * (1.0f / 768.0f) - mean * mean;
    var = fmaxf(var, 0.0f);
    const float inv = rsqrtf(var + 1e-12f);
#pragma unroll
    for (int i = 0; i < 3; ++i) {
        int c = t + i * 256;
        float vv = (i == 0) ? v0 : ((i == 1) ? v1 : v2);
        float y = (vv - mean) * inv * g[c] + be[c];
        outf[(size_t)row * H_ + c] = y;
        outb[(size_t)row * H_ + c] = f2bf(y);
    }
}

// ---------------- Flash attention, bf16 MFMA, KV-split x2 ----------------
// Grid: (S/64, NH, B), 512 threads = 8 waves. Waves 0-3 (half 0) process keys
// [0,512), waves 4-7 keys [512,1024) on private LDS halves; states merged at end.
__global__ __launch_bounds__(512) void fattn_k(
    const unsigned short* __restrict__ qkv,
    const unsigned short* __restrict__ madd,
    unsigned short* __restrict__ ctx)
{
    const int qt = blockIdx.x, h = blockIdx.y, b = blockIdx.z;
    const int q0 = qt * 64;
    const int t = threadIdx.x;
    const int w = t >> 6, lane = t & 63;
    const int half = w >> 2, w4 = w & 3;
    const int l15 = lane & 15;
    const int kr8 = (lane >> 4) * 8;
    const int rb  = (lane >> 4) * 4;
    const int wq0 = w4 * 16;

    // LDS carve: Ks[2][64][72] | VtL[2][4096] | Ps[2][64][72]
    __shared__ __align__(16) unsigned char smem[53248];
    unsigned short* KsH = (unsigned short*)(smem)         + (size_t)half * (64 * 72);
    unsigned short* VtH = (unsigned short*)(smem + 18432) + (size_t)half * 4096;
    unsigned short* PsH = (unsigned short*)(smem + 34816) + (size_t)half * (64 * 72);

    const size_t rstr = 2304;
    const unsigned short* base = qkv + (size_t)b * S_ * rstr + h * 64;

    // Q fragments (wave's 16 rows)
    v8s qf0, qf1;
    {
        const unsigned short* qp = base + (size_t)(q0 + wq0 + l15) * rstr + kr8;
        qf0 = *(const v8s*)qp;
        qf1 = *(const v8s*)(qp + 32);
    }

    // staging assignment (per half: 256 threads)
    const int tl  = t & 255;
    const int skp = tl >> 3;        // 0..31
    const int sd0 = (tl & 7) * 8;   // 0..56
    const unsigned short* kbase = base + 768  + (size_t)(half * 512 + skp) * rstr + sd0;
    const unsigned short* vbase = base + 1536 + (size_t)(half * 512 + 2 * skp) * rstr + sd0;
    const size_t kstep = (size_t)64 * rstr;

    float m_[4], l_[4];
    v4f accO[4];
#pragma unroll
    for (int i = 0; i < 4; ++i) { m_[i] = -3.0e38f; l_[i] = 0.f; }
#pragma unroll
    for (int f = 0; f < 4; ++f) accO[f] = (v4f){0.f, 0.f, 0.f, 0.f};

    const unsigned short* mrow[4];
#pragma unroll
    for (int i = 0; i < 4; ++i)
        mrow[i] = madd + ((size_t)(b * S_) + q0 + wq0 + rb + i) * S_ + half * 512;

    v8s kA0, kA1, vA0, vA1, kB0, kB1, vB0, vB1;
    // prefetch tile 0 -> set A
    kA0 = *(const v8s*)(kbase);
    kA1 = *(const v8s*)(kbase + 32 * rstr);
    vA0 = *(const v8s*)(vbase);
    vA1 = *(const v8s*)(vbase + rstr);

    for (int kt = 0; kt < 8; ++kt) {
        const int k0 = kt * 64;
        __syncthreads();
        // ---- write current regs -> LDS; issue next tile's loads ----
        if ((kt & 1) == 0) {
            *(v8s*)&KsH[skp * 72 + sd0] = kA0;
            *(v8s*)&KsH[(skp + 32) * 72 + sd0] = kA1;
#pragma unroll
            for (int j = 0; j < 8; ++j) {
                const int d = sd0 + j;
                const int sw = ((d & 7) ^ (d >> 3)) << 3;
                unsigned int pk = ((unsigned int)(unsigned short)vA1[j] << 16) | (unsigned short)vA0[j];
                *(unsigned int*)&VtH[(size_t)d * 64 + ((2 * skp) ^ sw)] = pk;
            }
            if (kt < 7) {
                const unsigned short* kp = kbase + (size_t)(kt + 1) * kstep;
                const unsigned short* vp = vbase + (size_t)(kt + 1) * kstep;
                kB0 = *(const v8s*)kp;
                kB1 = *(const v8s*)(kp + 32 * rstr);
                vB0 = *(const v8s*)vp;
                vB1 = *(const v8s*)(vp + rstr);
            }
        } else {
            *(v8s*)&KsH[skp * 72 + sd0] = kB0;
            *(v8s*)&KsH[(skp + 32) * 72 + sd0] = kB1;
#pragma unroll
            for (int j = 0; j < 8; ++j) {
                const int d = sd0 + j;
                const int sw = ((d & 7) ^ (d >> 3)) << 3;
                unsigned int pk = ((unsigned int)(unsigned short)vB1[j] << 16) | (unsigned short)vB0[j];
                *(unsigned int*)&VtH[(size_t)d * 64 + ((2 * skp) ^ sw)] = pk;
            }
            if (kt < 7) {
                const unsigned short* kp = kbase + (size_t)(kt + 1) * kstep;
                const unsigned short* vp = vbase + (size_t)(kt + 1) * kstep;
                kA0 = *(const v8s*)kp;
                kA1 = *(const v8s*)(kp + 32 * rstr);
                vA0 = *(const v8s*)vp;
                vA1 = *(const v8s*)(vp + rstr);
            }
        }
        __syncthreads();

        // ---- QK^T ----
        v4f s4[4];
#pragma unroll
        for (int f = 0; f < 4; ++f) s4[f] = (v4f){0.f, 0.f, 0.f, 0.f};
#pragma unroll
        for (int ks = 0; ks < 2; ++ks) {
            v8s qv = ks ? qf1 : qf0;
#pragma unroll
            for (int f = 0; f < 4; ++f) {
                v8s kf = *(const v8s*)&KsH[(f * 16 + l15) * 72 + ks * 32 + kr8];
                s4[f] = __builtin_amdgcn_mfma_f32_16x16x32_bf16(qv, kf, s4[f], 0, 0, 0);
            }
        }

        // ---- mask + scale + online softmax ----
        float p[4][4];
        float mx[4];
#pragma unroll
        for (int i = 0; i < 4; ++i) mx[i] = -3.0e38f;
#pragma unroll
        for (int f = 0; f < 4; ++f)
#pragma unroll
            for (int i = 0; i < 4; ++i) {
                float v = s4[f][i] * 0.125f + bf2f(mrow[i][k0 + f * 16 + l15]);
                p[f][i] = v;
                mx[i] = fmaxf(mx[i], v);
            }
#pragma unroll
        for (int o = 8; o; o >>= 1)
#pragma unroll
            for (int i = 0; i < 4; ++i) mx[i] = fmaxf(mx[i], __shfl_xor(mx[i], o));
        float corr[4], rsum[4];
#pragma unroll
        for (int i = 0; i < 4; ++i) {
            float mn = fmaxf(m_[i], mx[i]);
            corr[i] = __expf(m_[i] - mn);
            m_[i] = mn;
            rsum[i] = 0.f;
        }
#pragma unroll
        for (int f = 0; f < 4; ++f)
#pragma unroll
            for (int i = 0; i < 4; ++i) {
                float e = __expf(p[f][i] - m_[i]);
                p[f][i] = e;
                rsum[i] += e;
            }
#pragma unroll
        for (int o = 8; o; o >>= 1)
#pragma unroll
            for (int i = 0; i < 4; ++i) rsum[i] += __shfl_xor(rsum[i], o);
#pragma unroll
        for (int i = 0; i < 4; ++i) l_[i] = l_[i] * corr[i] + rsum[i];
#pragma unroll
        for (int f = 0; f < 4; ++f)
#pragma unroll
            for (int i = 0; i < 4; ++i) accO[f][i] *= corr[i];

        // ---- P -> LDS (wave-private rows) ----
#pragma unroll
        for (int f = 0; f < 4; ++f)
#pragma unroll
            for (int i = 0; i < 4; ++i)
                PsH[(wq0 + rb + i) * 72 + f * 16 + l15] = f2bf(p[f][i]);

        // ---- PV ----
#pragma unroll
        for (int ks = 0; ks < 2; ++ks) {
            v8s pf = *(const v8s*)&PsH[(wq0 + l15) * 72 + ks * 32 + kr8];
#pragma unroll
            for (int f = 0; f < 4; ++f) {
                const int d = f * 16 + l15;
                const int sw = ((d & 7) ^ (d >> 3)) << 3;
                v8s vf = *(const v8s*)&VtH[(size_t)d * 64 + ((ks * 32 + kr8) ^ sw)];
                accO[f] = __builtin_amdgcn_mfma_f32_16x16x32_bf16(pf, vf, accO[f], 0, 0, 0);
            }
        }
    }

    // ---- merge the two KV-halves (online-softmax state merge) ----
    __syncthreads();
    float* Mb = (float*)smem;   // [4][64][26] floats, overlays Ks/Vt (dead now)
    const int mstr = 26;
    if (half == 1) {
        float* p = Mb + ((size_t)(w4 * 64 + lane)) * mstr;
#pragma unroll
        for (int i = 0; i < 4; ++i) { p[i] = m_[i]; p[4 + i] = l_[i]; }
#pragma unroll
        for (int f = 0; f < 4; ++f)
#pragma unroll
            for (int i = 0; i < 4; ++i) p[8 + f * 4 + i] = accO[f][i];
    }
    __syncthreads();
    if (half == 0) {
        const float* p = Mb + ((size_t)(w4 * 64 + lane)) * mstr;
        float c0[4], c1[4];
#pragma unroll
        for (int i = 0; i < 4; ++i) {
            float m1 = p[i], l1 = p[4 + i];
            float mm = fmaxf(m_[i], m1);
            c0[i] = __expf(m_[i] - mm);
            c1[i] = __expf(m1 - mm);
            l_[i] = l_[i] * c0[i] + l1 * c1[i];
            m_[i] = mm;
        }
#pragma unroll
        for (int f = 0; f < 4; ++f)
#pragma unroll
            for (int i = 0; i < 4; ++i) {
                float o = (accO[f][i] * c0[i] + p[8 + f * 4 + i] * c1[i]) / l_[i];
                size_t row = (size_t)(b * S_) + q0 + wq0 + rb + i;
                ctx[row * 768 + h * 64 + f * 16 + l15] = f2bf(o);
            }
    }
}

extern "C" void kernel_launch(void* const* d_in, const int* in_sizes, int n_in,
                              void* d_out, int out_size, void* d_ws, size_t ws_size,
                              hipStream_t stream)
{
    const float* x   = (const float*)d_in[0];
    const int*   mask= (const int*)  d_in[1];
    const float* Wq  = (const float*)d_in[2];
    const float* bq  = (const float*)d_in[3];
    const float* Wk  = (const float*)d_in[4];
    const float* bk  = (const float*)d_in[5];
    const float* Wv  = (const float*)d_in[6];
    const float* bv  = (const float*)d_in[7];
    const float* Wao = (const float*)d_in[8];
    const float* bao = (const float*)d_in[9];
    const float* g1  = (const float*)d_in[10];
    const float* b1  = (const float*)d_in[11];
    const float* Wi  = (const float*)d_in[12];
    const float* bi  = (const float*)d_in[13];
    const float* Wfo = (const float*)d_in[14];
    const float* bfo = (const float*)d_in[15];
    const float* g2  = (const float*)d_in[16];
    const float* b2  = (const float*)d_in[17];
    float* out = (float*)d_out;

    const int M = B_ * S_; // 2048
    char* basep = (char*)d_ws;
    size_t off = 0;
    auto alloc = [&](size_t bytes) -> char* {
        char* p = basep + off;
        off = (off + bytes + 255) & ~(size_t)255;
        return p;
    };

    unsigned short* WqkvT = (unsigned short*)alloc((size_t)L_ * 2304 * 768 * 2);
    unsigned short* WaoT  = (unsigned short*)alloc((size_t)L_ * 768 * 768 * 2);
    unsigned short* WiT   = (unsigned short*)alloc((size_t)L_ * 3072 * 768 * 2);
    unsigned short* WfoT  = (unsigned short*)alloc((size_t)L_ * 768 * 3072 * 2);
    unsigned short* h_bf  = (unsigned short*)alloc((size_t)M * 768 * 2);
    unsigned short* qkvbf = (unsigned short*)alloc((size_t)M * 2304 * 2);  // t1b aliases this (dead when used)
    unsigned short* ctxbf = (unsigned short*)alloc((size_t)M * 768 * 2);
    float* t1a            = (float*)alloc((size_t)M * 768 * 4);
    float* attnf          = (float*)alloc((size_t)M * 768 * 4);
    unsigned short* attnbf= (unsigned short*)alloc((size_t)M * 768 * 2);
    unsigned short* interbf = (unsigned short*)alloc((size_t)M * FF_ * 2);
    unsigned short* madd  = (unsigned short*)alloc((size_t)B_ * S_ * S_ * 2);
    float* t1b = (float*)(void*)qkvbf;   // alias: qkvbf dead during AO/FFN2/LN
    // rolling hidden state (fp32) lives in d_out; final layer's LN2 writes the answer

    dim3 tb(256);
    transpose_convert<<<dim3(24, 24, L_), tb, 0, stream>>>(Wq,  WqkvT + 0,          768,  768, (size_t)768 * 768,  (size_t)2304 * 768);
    transpose_convert<<<dim3(24, 24, L_), tb, 0, stream>>>(Wk,  WqkvT + 768 * 768,  768,  768, (size_t)768 * 768,  (size_t)2304 * 768);
    transpose_convert<<<dim3(24, 24, L_), tb, 0, stream>>>(Wv,  WqkvT + 1536 * 768, 768,  768, (size_t)768 * 768,  (size_t)2304 * 768);
    transpose_convert<<<dim3(24, 24, L_), tb, 0, stream>>>(Wao, WaoT,               768,  768, (size_t)768 * 768,  (size_t)768 * 768);
    transpose_convert<<<dim3(24, 96, L_), tb, 0, stream>>>(Wi,  WiT,                768, 3072, (size_t)768 * 3072, (size_t)3072 * 768);
    transpose_convert<<<dim3(96, 24, L_), tb, 0, stream>>>(Wfo, WfoT,              3072,  768, (size_t)3072 * 768, (size_t)768 * 3072);

    conv_bf16_k<<<(M * 768 + 255) / 256, 256, 0, stream>>>(x, h_bf, M * 768);
    maskconv_k<<<(B_ * S_ * S_ + 255) / 256, 256, 0, stream>>>(mask, madd, B_ * S_ * S_);

    const float* hres = x;
    for (int l = 0; l < L_; ++l) {
        // QKV projection (fused, N=2304, bf16 out)
        gemm_k<0, 1, 3, 0><<<dim3(16, 36), tb, 0, stream>>>(
            h_bf, WqkvT + (size_t)l * 2304 * 768,
            bq + l * 768, bk + l * 768, bv + l * 768, nullptr, qkvbf, nullptr, M, 2304, 768, 768);
        // Flash attention (bf16 MFMA, KV-split x2)
        fattn_k<<<dim3(S_ / 64, NH_, B_), dim3(512), 0, stream>>>(qkvbf, madd, ctxbf);
        // Attention output projection + residual, split-K x2
        gemm_k<0, 0, 1, 1><<<dim3(16, 12, 2), tb, 0, stream>>>(
            ctxbf, WaoT + (size_t)l * 768 * 768,
            bao + l * 768, nullptr, nullptr, hres, t1a, t1b, M, 768, 768, 384);
        ln_k<<<M, tb, 0, stream>>>(t1a, t1b, g1 + l * 768, b1 + l * 768, attnf, attnbf);
        // FFN1 + GELU (bf16 out)
        gemm_k<1, 1, 1, 0><<<dim3(16, 48), tb, 0, stream>>>(
            attnbf, WiT + (size_t)l * 3072 * 768,
            bi + l * 3072, nullptr, nullptr, nullptr, interbf, nullptr, M, 3072, 768, 768);
        // FFN2 + residual, split-K x2
        gemm_k<0, 0, 1, 1><<<dim3(16, 12, 2), tb, 0, stream>>>(
            interbf, WfoT + (size_t)l * 3072 * 768,
            bfo + l * 768, nullptr, nullptr, attnf, t1a, t1b, M, 768, 3072, 1536);
        ln_k<<<M, tb, 0, stream>>>(t1a, t1b, g2 + l * 768, b2 + l * 768, out, h_bf);
        hres = out;
    }
}

// Round 8
// 734.076 us; speedup vs baseline: 1.3827x; 1.0473x over previous
//
#include <hip/hip_runtime.h>
#include <math.h>

// Problem dims
#define B_  2
#define S_  1024
#define H_  768
#define NH_ 12
#define DH_ 64
#define FF_ 3072
#define L_  4

typedef short v8s __attribute__((ext_vector_type(8)));
typedef float v4f __attribute__((ext_vector_type(4)));

static __device__ __forceinline__ unsigned short f2bf(float f) {
    unsigned int u = __float_as_uint(f);
    unsigned int r = (u + 0x7fffu + ((u >> 16) & 1u)) >> 16;
    return (unsigned short)r;
}
static __device__ __forceinline__ float bf2f(unsigned short u) {
    return __uint_as_float((unsigned int)u << 16);
}

#define GLOAD16(g, l) __builtin_amdgcn_global_load_lds( \
    (const __attribute__((address_space(1))) unsigned int*)(g), \
    (__attribute__((address_space(3))) unsigned int*)(l), 16, 0, 0)

// ---------------- fp32 -> bf16 convert ----------------
__global__ void conv_bf16_k(const float* __restrict__ in, unsigned short* __restrict__ out, int n) {
    int i = blockIdx.x * 256 + threadIdx.x;
    if (i < n) out[i] = f2bf(in[i]);
}

// ---------------- mask -> additive bf16, exp2 units (-10000*log2e ~ -14400) --
__global__ void maskconv_k(const int* __restrict__ m, unsigned short* __restrict__ o, int n) {
    int i = blockIdx.x * 256 + threadIdx.x;
    if (i < n) o[i] = m[i] ? (unsigned short)0u : (unsigned short)0xC661u; // -14400
}

// ---------------- fp32 [K,N] -> bf16 [N,K] transpose-convert ----------------
__global__ __launch_bounds__(256) void transpose_convert(
    const float* __restrict__ W, unsigned short* __restrict__ Wt,
    int K, int N, size_t in_lstride, size_t out_lstride)
{
    __shared__ float tile[32][33];
    const int l = blockIdx.z;
    const float* src = W + (size_t)l * in_lstride;
    unsigned short* dst = Wt + (size_t)l * out_lstride;
    const int k0 = blockIdx.x * 32;
    const int n0 = blockIdx.y * 32;
    const int t = threadIdx.x;
    const int tc = t & 31, tr = t >> 5;
#pragma unroll
    for (int i = 0; i < 4; ++i) {
        int r = tr + i * 8;
        tile[r][tc] = src[(size_t)(k0 + r) * N + n0 + tc];
    }
    __syncthreads();
#pragma unroll
    for (int i = 0; i < 4; ++i) {
        int r = tr + i * 8;
        dst[(size_t)(n0 + r) * K + k0 + tc] = f2bf(tile[tc][r]);
    }
}

// ---------------- bf16 MFMA GEMM, 128x64 tile, BK=64, 2-phase dbuf ----------
template<int ACT, int OUT_BF, int NBIAS, int SPLIT>
__global__ __launch_bounds__(256) void gemm_k(
    const unsigned short* __restrict__ A,
    const unsigned short* __restrict__ Bt,
    const float* __restrict__ b0,
    const float* __restrict__ b1,
    const float* __restrict__ b2,
    const float* __restrict__ res,
    void* __restrict__ out0,
    float* __restrict__ out1,
    int M, int N, int K, int klen)
{
    __shared__ __align__(16) unsigned short As[2][128 * 64];
    __shared__ __align__(16) unsigned short Bs[2][64 * 64];
    const int t = threadIdx.x;
    const int m0 = blockIdx.x * 128;
    const int n0 = blockIdx.y * 64;
    const int kz = SPLIT ? blockIdx.z : 0;
    const int kstart = kz * klen;
    const int lane = t & 63;
    const int w = t >> 6;
    const int wm = w >> 1, wn = w & 1;
    const int l15 = lane & 15;
    const int q4  = lane >> 4;      // 0..3

    const unsigned short* gA[4];
    const unsigned short* gB[2];
#pragma unroll
    for (int i = 0; i < 4; ++i) {
        int c = t + i * 256;
        int r = c >> 3, cc = c & 7;
        gA[i] = A + (size_t)(m0 + r) * K + kstart + ((cc ^ (r & 7)) << 3);
    }
#pragma unroll
    for (int i = 0; i < 2; ++i) {
        int c = t + i * 256;
        int r = c >> 3, cc = c & 7;
        gB[i] = Bt + (size_t)(n0 + r) * K + kstart + ((cc ^ (r & 7)) << 3);
    }
    const int ldsW = w * 512;

    v4f acc[4][2] = {};
    const int nt = klen >> 6;

#pragma unroll
    for (int i = 0; i < 4; ++i) GLOAD16(gA[i], &As[0][i * 2048 + ldsW]);
#pragma unroll
    for (int i = 0; i < 2; ++i) GLOAD16(gB[i], &Bs[0][i * 2048 + ldsW]);

    int cur = 0;
    for (int kt = 0; kt < nt; ++kt) {
        __syncthreads();
        if (kt + 1 < nt) {
            const size_t go = (size_t)(kt + 1) << 6;
#pragma unroll
            for (int i = 0; i < 4; ++i) GLOAD16(gA[i] + go, &As[cur ^ 1][i * 2048 + ldsW]);
#pragma unroll
            for (int i = 0; i < 2; ++i) GLOAD16(gB[i] + go, &Bs[cur ^ 1][i * 2048 + ldsW]);
        }
        const unsigned short* as = As[cur];
        const unsigned short* bs = Bs[cur];
#pragma unroll
        for (int ks = 0; ks < 2; ++ks) {
            v8s af[4], bf[2];
#pragma unroll
            for (int i = 0; i < 4; ++i) {
                int r = wm * 64 + i * 16 + l15;
                af[i] = *(const v8s*)&as[r * 64 + ((((ks << 2) + q4) ^ (r & 7)) << 3)];
            }
#pragma unroll
            for (int i = 0; i < 2; ++i) {
                int r = wn * 32 + i * 16 + l15;
                bf[i] = *(const v8s*)&bs[r * 64 + ((((ks << 2) + q4) ^ (r & 7)) << 3)];
            }
#pragma unroll
            for (int fm = 0; fm < 4; ++fm)
#pragma unroll
                for (int fn = 0; fn < 2; ++fn)
                    acc[fm][fn] = __builtin_amdgcn_mfma_f32_16x16x32_bf16(af[fm], bf[fn], acc[fm][fn], 0, 0, 0);
        }
        cur ^= 1;
    }

    const int rb = q4 * 4;
#pragma unroll
    for (int fm = 0; fm < 4; ++fm)
#pragma unroll
        for (int fn = 0; fn < 2; ++fn)
#pragma unroll
            for (int i = 0; i < 4; ++i) {
                const int row = m0 + wm * 64 + fm * 16 + rb + i;
                const int col = n0 + wn * 32 + fn * 16 + l15;
                float v = acc[fm][fn][i];
                const size_t oi = (size_t)row * N + col;
                if (!SPLIT || kz == 0) {
                    float bb;
                    if (NBIAS == 3) {
                        int which = (col >= 1536) ? 2 : (col >= 768 ? 1 : 0);
                        const float* bp = (which == 0) ? b0 : ((which == 1) ? b1 : b2);
                        bb = bp[col - which * 768];
                    } else {
                        bb = b0[col];
                    }
                    v += bb;
                    if (res) v += res[oi];
                    if (ACT == 1) v = 0.5f * v * (1.0f + erff(v * 0.70710678118654752f));
                    if (OUT_BF) ((unsigned short*)out0)[oi] = f2bf(v);
                    else        ((float*)out0)[oi] = v;
                } else {
                    out1[oi] = v;
                }
            }
}

// ---------------- LayerNorm (row = 768), x = ina + inb, writes fp32 + bf16 ----
__global__ __launch_bounds__(256) void ln_k(
    const float* __restrict__ ina, const float* __restrict__ inb,
    const float* __restrict__ g, const float* __restrict__ be,
    float* __restrict__ outf, unsigned short* __restrict__ outb)
{
    const int row = blockIdx.x;
    const float* xa = ina + (size_t)row * H_;
    const float* xb = inb + (size_t)row * H_;
    const int t = threadIdx.x;
    const int wave = t >> 6, lane = t & 63;
    float v0 = xa[t] + xb[t];
    float v1 = xa[t + 256] + xb[t + 256];
    float v2 = xa[t + 512] + xb[t + 512];
    float s = v0 + v1 + v2;
    float s2 = v0 * v0 + v1 * v1 + v2 * v2;
#pragma unroll
    for (int o = 32; o; o >>= 1) { s += __shfl_xor(s, o); s2 += __shfl_xor(s2, o); }
    __shared__ float rs[4], rq[4];
    if (lane == 0) { rs[wave] = s; rq[wave] = s2; }
    __syncthreads();
    s  = rs[0] + rs[1] + rs[2] + rs[3];
    s2 = rq[0] + rq[1] + rq[2] + rq[3];
    const float mean = s * (1.0f / 768.0f);
    float var = s2 * (1.0f / 768.0f) - mean * mean;
    var = fmaxf(var, 0.0f);
    const float inv = rsqrtf(var + 1e-12f);
#pragma unroll
    for (int i = 0; i < 3; ++i) {
        int c = t + i * 256;
        float vv = (i == 0) ? v0 : ((i == 1) ? v1 : v2);
        float y = (vv - mean) * inv * g[c] + be[c];
        outf[(size_t)row * H_ + c] = y;
        outb[(size_t)row * H_ + c] = f2bf(y);
    }
}

// ---------------- Flash attention partial, bf16 MFMA, KV-split across blocks -
// Grid: (S/64, NH, B*2); blockIdx.z = b*2 + kvh. 256 threads = 4 waves, each
// wave owns 16 q-rows; block processes keys [kvh*512, kvh*512+512) (8 tiles).
// Softmax in exp2 domain (scale and mask pre-multiplied by log2e).
// Outputs UNDIVIDED partial O (fp32) + per-(row,h) running (m,l) for merge.
__global__ __launch_bounds__(256) void fattn_k(
    const unsigned short* __restrict__ qkv,
    const unsigned short* __restrict__ madd,
    float* __restrict__ pO,      // [2][B*S][768]
    float* __restrict__ pML)     // [2][B*S][NH][2]
{
    const int qt = blockIdx.x, h = blockIdx.y, zz = blockIdx.z;
    const int b = zz >> 1, kvh = zz & 1;
    const int q0 = qt * 64;
    const int t = threadIdx.x;
    const int w = t >> 6, lane = t & 63;
    const int l15 = lane & 15;
    const int kr8 = (lane >> 4) * 8;
    const int rb  = (lane >> 4) * 4;
    const int wq0 = w * 16;

    __shared__ __align__(16) unsigned short Ks[64][72];
    __shared__ __align__(16) unsigned short Vt[4096];
    __shared__ __align__(16) unsigned short Ps[64][72];

    const size_t rstr = 2304;
    const unsigned short* base = qkv + (size_t)b * S_ * rstr + h * 64;

    // Q fragments (wave's 16 rows)
    v8s qf0, qf1;
    {
        const unsigned short* qp = base + (size_t)(q0 + wq0 + l15) * rstr + kr8;
        qf0 = *(const v8s*)qp;
        qf1 = *(const v8s*)(qp + 32);
    }

    // staging assignment
    const int skp = t >> 3;        // 0..31
    const int sd0 = (t & 7) * 8;   // 0..56
    const unsigned short* kbase = base + 768  + (size_t)(kvh * 512 + skp) * rstr + sd0;
    const unsigned short* vbase = base + 1536 + (size_t)(kvh * 512 + 2 * skp) * rstr + sd0;
    const size_t kstep = (size_t)64 * rstr;

    float m_[4], l_[4];
    v4f accO[4];
#pragma unroll
    for (int i = 0; i < 4; ++i) { m_[i] = -3.0e38f; l_[i] = 0.f; }
#pragma unroll
    for (int f = 0; f < 4; ++f) accO[f] = (v4f){0.f, 0.f, 0.f, 0.f};

    const unsigned short* mrow[4];
#pragma unroll
    for (int i = 0; i < 4; ++i)
        mrow[i] = madd + ((size_t)(b * S_) + q0 + wq0 + rb + i) * S_ + kvh * 512;

    v8s kA0, kA1, vA0, vA1, kB0, kB1, vB0, vB1;
    kA0 = *(const v8s*)(kbase);
    kA1 = *(const v8s*)(kbase + 32 * rstr);
    vA0 = *(const v8s*)(vbase);
    vA1 = *(const v8s*)(vbase + rstr);

    const float SC2 = 0.18033688011112042f;   // 0.125 * log2(e)

    for (int kt = 0; kt < 8; ++kt) {
        const int k0 = kt * 64;
        // mask prefetch for THIS tile: register loads are not drained by the
        // barriers (only their use waits) -> latency hides under staging + QK^T
        unsigned short mu[16];
#pragma unroll
        for (int f = 0; f < 4; ++f)
#pragma unroll
            for (int i = 0; i < 4; ++i)
                mu[f * 4 + i] = mrow[i][k0 + f * 16 + l15];

        __syncthreads();
        if ((kt & 1) == 0) {
            *(v8s*)&Ks[skp][sd0] = kA0;
            *(v8s*)&Ks[skp + 32][sd0] = kA1;
#pragma unroll
            for (int j = 0; j < 8; ++j) {
                const int d = sd0 + j;
                const int sw = ((d & 7) ^ (d >> 3)) << 3;
                unsigned int pk = ((unsigned int)(unsigned short)vA1[j] << 16) | (unsigned short)vA0[j];
                *(unsigned int*)&Vt[(size_t)d * 64 + ((2 * skp) ^ sw)] = pk;
            }
            if (kt < 7) {
                const unsigned short* kp = kbase + (size_t)(kt + 1) * kstep;
                const unsigned short* vp = vbase + (size_t)(kt + 1) * kstep;
                kB0 = *(const v8s*)kp;
                kB1 = *(const v8s*)(kp + 32 * rstr);
                vB0 = *(const v8s*)vp;
                vB1 = *(const v8s*)(vp + rstr);
            }
        } else {
            *(v8s*)&Ks[skp][sd0] = kB0;
            *(v8s*)&Ks[skp + 32][sd0] = kB1;
#pragma unroll
            for (int j = 0; j < 8; ++j) {
                const int d = sd0 + j;
                const int sw = ((d & 7) ^ (d >> 3)) << 3;
                unsigned int pk = ((unsigned int)(unsigned short)vB1[j] << 16) | (unsigned short)vB0[j];
                *(unsigned int*)&Vt[(size_t)d * 64 + ((2 * skp) ^ sw)] = pk;
            }
            if (kt < 7) {
                const unsigned short* kp = kbase + (size_t)(kt + 1) * kstep;
                const unsigned short* vp = vbase + (size_t)(kt + 1) * kstep;
                kA0 = *(const v8s*)kp;
                kA1 = *(const v8s*)(kp + 32 * rstr);
                vA0 = *(const v8s*)vp;
                vA1 = *(const v8s*)(vp + rstr);
            }
        }
        __syncthreads();

        // ---- QK^T ----
        v4f s4[4];
#pragma unroll
        for (int f = 0; f < 4; ++f) s4[f] = (v4f){0.f, 0.f, 0.f, 0.f};
#pragma unroll
        for (int ks = 0; ks < 2; ++ks) {
            v8s qv = ks ? qf1 : qf0;
#pragma unroll
            for (int f = 0; f < 4; ++f) {
                v8s kf = *(const v8s*)&Ks[f * 16 + l15][ks * 32 + kr8];
                s4[f] = __builtin_amdgcn_mfma_f32_16x16x32_bf16(qv, kf, s4[f], 0, 0, 0);
            }
        }

        // ---- mask + scale + online softmax (exp2 domain) ----
        float p[4][4];
        float mx[4];
#pragma unroll
        for (int i = 0; i < 4; ++i) mx[i] = -3.0e38f;
#pragma unroll
        for (int f = 0; f < 4; ++f)
#pragma unroll
            for (int i = 0; i < 4; ++i) {
                float v = s4[f][i] * SC2 + bf2f(mu[f * 4 + i]);
                p[f][i] = v;
                mx[i] = fmaxf(mx[i], v);
            }
#pragma unroll
        for (int o = 8; o; o >>= 1)
#pragma unroll
            for (int i = 0; i < 4; ++i) mx[i] = fmaxf(mx[i], __shfl_xor(mx[i], o));
        float corr[4], rsum[4];
#pragma unroll
        for (int i = 0; i < 4; ++i) {
            float mn = fmaxf(m_[i], mx[i]);
            corr[i] = exp2f(m_[i] - mn);
            m_[i] = mn;
            rsum[i] = 0.f;
        }
#pragma unroll
        for (int f = 0; f < 4; ++f)
#pragma unroll
            for (int i = 0; i < 4; ++i) {
                float e = exp2f(p[f][i] - m_[i]);
                p[f][i] = e;
                rsum[i] += e;
            }
#pragma unroll
        for (int o = 8; o; o >>= 1)
#pragma unroll
            for (int i = 0; i < 4; ++i) rsum[i] += __shfl_xor(rsum[i], o);
#pragma unroll
        for (int i = 0; i < 4; ++i) l_[i] = l_[i] * corr[i] + rsum[i];
#pragma unroll
        for (int f = 0; f < 4; ++f)
#pragma unroll
            for (int i = 0; i < 4; ++i) accO[f][i] *= corr[i];

        // ---- P -> LDS (wave-private rows) ----
#pragma unroll
        for (int f = 0; f < 4; ++f)
#pragma unroll
            for (int i = 0; i < 4; ++i)
                Ps[wq0 + rb + i][f * 16 + l15] = f2bf(p[f][i]);

        // ---- PV ----
#pragma unroll
        for (int ks = 0; ks < 2; ++ks) {
            v8s pf = *(const v8s*)&Ps[wq0 + l15][ks * 32 + kr8];
#pragma unroll
            for (int f = 0; f < 4; ++f) {
                const int d = f * 16 + l15;
                const int sw = ((d & 7) ^ (d >> 3)) << 3;
                v8s vf = *(const v8s*)&Vt[(size_t)d * 64 + ((ks * 32 + kr8) ^ sw)];
                accO[f] = __builtin_amdgcn_mfma_f32_16x16x32_bf16(pf, vf, accO[f], 0, 0, 0);
            }
        }
    }

    // ---- store partial O (undivided) + states ----
    float* po = pO + (size_t)kvh * (2048 * 768);
#pragma unroll
    for (int f = 0; f < 4; ++f)
#pragma unroll
        for (int i = 0; i < 4; ++i) {
            size_t row = (size_t)(b * S_) + q0 + wq0 + rb + i;
            po[row * 768 + h * 64 + f * 16 + l15] = accO[f][i];
        }
    if (l15 == 0) {
#pragma unroll
        for (int i = 0; i < 4; ++i) {
            size_t row = (size_t)(b * S_) + q0 + wq0 + rb + i;
            size_t idx = (((size_t)kvh * 2048 + row) * NH_ + h) * 2;
            pML[idx] = m_[i];
            pML[idx + 1] = l_[i];
        }
    }
}

// ---------------- merge the two KV-half partials -> ctx bf16 ----------------
__global__ __launch_bounds__(256) void attn_merge(
    const float* __restrict__ pO, const float* __restrict__ pML,
    unsigned short* __restrict__ ctx)
{
    const int i = blockIdx.x * 256 + threadIdx.x;   // 393216 threads, 4 cols each
    const int row = i / 192;
    const int c4 = (i - row * 192) * 4;
    const int h = c4 >> 6;
    const size_t mi0 = ((size_t)row * NH_ + h) * 2;
    const size_t mi1 = (((size_t)2048 + row) * NH_ + h) * 2;
    const float m0 = pML[mi0], l0 = pML[mi0 + 1];
    const float m1 = pML[mi1], l1 = pML[mi1 + 1];
    const float mm = fmaxf(m0, m1);
    const float c0 = exp2f(m0 - mm), c1 = exp2f(m1 - mm);
    const float inv = 1.0f / (l0 * c0 + l1 * c1);
    const size_t off = (size_t)row * 768 + c4;
    float4 o0 = *(const float4*)&pO[off];
    float4 o1 = *(const float4*)&pO[(size_t)2048 * 768 + off];
    unsigned short r[4];
    r[0] = f2bf((o0.x * c0 + o1.x * c1) * inv);
    r[1] = f2bf((o0.y * c0 + o1.y * c1) * inv);
    r[2] = f2bf((o0.z * c0 + o1.z * c1) * inv);
    r[3] = f2bf((o0.w * c0 + o1.w * c1) * inv);
    *(uint2*)&ctx[off] = *(uint2*)r;
}

extern "C" void kernel_launch(void* const* d_in, const int* in_sizes, int n_in,
                              void* d_out, int out_size, void* d_ws, size_t ws_size,
                              hipStream_t stream)
{
    const float* x   = (const float*)d_in[0];
    const int*   mask= (const int*)  d_in[1];
    const float* Wq  = (const float*)d_in[2];
    const float* bq  = (const float*)d_in[3];
    const float* Wk  = (const float*)d_in[4];
    const float* bk  = (const float*)d_in[5];
    const float* Wv  = (const float*)d_in[6];
    const float* bv  = (const float*)d_in[7];
    const float* Wao = (const float*)d_in[8];
    const float* bao = (const float*)d_in[9];
    const float* g1  = (const float*)d_in[10];
    const float* b1  = (const float*)d_in[11];
    const float* Wi  = (const float*)d_in[12];
    const float* bi  = (const float*)d_in[13];
    const float* Wfo = (const float*)d_in[14];
    const float* bfo = (const float*)d_in[15];
    const float* g2  = (const float*)d_in[16];
    const float* b2  = (const float*)d_in[17];
    float* out = (float*)d_out;

    const int M = B_ * S_; // 2048
    char* basep = (char*)d_ws;
    size_t off = 0;
    auto alloc = [&](size_t bytes) -> char* {
        char* p = basep + off;
        off = (off + bytes + 255) & ~(size_t)255;
        return p;
    };

    unsigned short* WqkvT = (unsigned short*)alloc((size_t)L_ * 2304 * 768 * 2);
    unsigned short* WaoT  = (unsigned short*)alloc((size_t)L_ * 768 * 768 * 2);
    unsigned short* WiT   = (unsigned short*)alloc((size_t)L_ * 3072 * 768 * 2);
    unsigned short* WfoT  = (unsigned short*)alloc((size_t)L_ * 768 * 3072 * 2);
    unsigned short* h_bf  = (unsigned short*)alloc((size_t)M * 768 * 2);
    unsigned short* qkvbf = (unsigned short*)alloc((size_t)M * 2304 * 2);  // t1b aliases this
    unsigned short* ctxbf = (unsigned short*)alloc((size_t)M * 768 * 2);
    float* t1a            = (float*)alloc((size_t)M * 768 * 4);            // pML aliases this
    float* attnf          = (float*)alloc((size_t)M * 768 * 4);
    unsigned short* attnbf= (unsigned short*)alloc((size_t)M * 768 * 2);
    unsigned short* interbf = (unsigned short*)alloc((size_t)M * FF_ * 2); // pO aliases this
    unsigned short* madd  = (unsigned short*)alloc((size_t)B_ * S_ * S_ * 2);
    float* t1b = (float*)(void*)qkvbf;     // qkvbf dead during AO/FFN2/LN
    float* pO  = (float*)(void*)interbf;   // interbf dead during attention (12.58MB exact fit)
    float* pML = t1a;                      // t1a dead during attention

    dim3 tb(256);
    transpose_convert<<<dim3(24, 24, L_), tb, 0, stream>>>(Wq,  WqkvT + 0,          768,  768, (size_t)768 * 768,  (size_t)2304 * 768);
    transpose_convert<<<dim3(24, 24, L_), tb, 0, stream>>>(Wk,  WqkvT + 768 * 768,  768,  768, (size_t)768 * 768,  (size_t)2304 * 768);
    transpose_convert<<<dim3(24, 24, L_), tb, 0, stream>>>(Wv,  WqkvT + 1536 * 768, 768,  768, (size_t)768 * 768,  (size_t)2304 * 768);
    transpose_convert<<<dim3(24, 24, L_), tb, 0, stream>>>(Wao, WaoT,               768,  768, (size_t)768 * 768,  (size_t)768 * 768);
    transpose_convert<<<dim3(24, 96, L_), tb, 0, stream>>>(Wi,  WiT,                768, 3072, (size_t)768 * 3072, (size_t)3072 * 768);
    transpose_convert<<<dim3(96, 24, L_), tb, 0, stream>>>(Wfo, WfoT,              3072,  768, (size_t)3072 * 768, (size_t)768 * 3072);

    conv_bf16_k<<<(M * 768 + 255) / 256, 256, 0, stream>>>(x, h_bf, M * 768);
    maskconv_k<<<(B_ * S_ * S_ + 255) / 256, 256, 0, stream>>>(mask, madd, B_ * S_ * S_);

    const float* hres = x;
    for (int l = 0; l < L_; ++l) {
        // QKV projection (fused, N=2304, bf16 out)
        gemm_k<0, 1, 3, 0><<<dim3(16, 36), tb, 0, stream>>>(
            h_bf, WqkvT + (size_t)l * 2304 * 768,
            bq + l * 768, bk + l * 768, bv + l * 768, nullptr, qkvbf, nullptr, M, 2304, 768, 768);
        // Flash attention partials (KV-split across blocks) + merge
        fattn_k<<<dim3(S_ / 64, NH_, B_ * 2), tb, 0, stream>>>(qkvbf, madd, pO, pML);
        attn_merge<<<1536, tb, 0, stream>>>(pO, pML, ctxbf);
        // Attention output projection + residual, split-K x2
        gemm_k<0, 0, 1, 1><<<dim3(16, 12, 2), tb, 0, stream>>>(
            ctxbf, WaoT + (size_t)l * 768 * 768,
            bao + l * 768, nullptr, nullptr, hres, t1a, t1b, M, 768, 768, 384);
        ln_k<<<M, tb, 0, stream>>>(t1a, t1b, g1 + l * 768, b1 + l * 768, attnf, attnbf);
        // FFN1 + GELU (bf16 out)
        gemm_k<1, 1, 1, 0><<<dim3(16, 48), tb, 0, stream>>>(
            attnbf, WiT + (size_t)l * 3072 * 768,
            bi + l * 3072, nullptr, nullptr, nullptr, interbf, nullptr, M, 3072, 768, 768);
        // FFN2 + residual, split-K x2
        gemm_k<0, 0, 1, 1><<<dim3(16, 12, 2), tb, 0, stream>>>(
            interbf, WfoT + (size_t)l * 3072 * 768,
            bfo + l * 768, nullptr, nullptr, attnf, t1a, t1b, M, 768, 3072, 1536);
        ln_k<<<M, tb, 0, stream>>>(t1a, t1b, g2 + l * 768, b2 + l * 768, out, h_bf);
        hres = out;
    }
}